// Round 20
// baseline (163.926 us; speedup 1.0000x reference)
//
#include <hip/hip_runtime.h>

#define NB 8
#define N1 8192
#define N2 2048
#define C1 256
#define C2 512
#define CO 768   // C1 + C2
#define CCH 4    // channels per interp block
#define IREPS 4  // interp body repetition (instrumentation round)

typedef float f2 __attribute__((ext_vector_type(2)));
typedef float f4 __attribute__((ext_vector_type(4)));

// ws: keys4 (B*N2 float4 = 256 KB) | nn_idx (B*N1*4 ints = 1 MB) |
//     nn_w (B*N1*4 floats = 1 MB). Total 2.25 MB.  (R11..R18-exact layout)

// ---------------------------------------------------------------------------
// ASM-PINNED arithmetic — VERBATIM R14..R18 (validated, absmax 0.015625).
// ---------------------------------------------------------------------------
#define NRM2(X, Y, Z) ({                                                   \
    float _s, _t;                                                          \
    asm("v_mul_f32 %0, %2, %2\n\t"                                         \
        "v_mul_f32 %1, %3, %3\n\t"                                         \
        "v_add_f32 %0, %0, %1\n\t"                                         \
        "v_mul_f32 %1, %4, %4\n\t"                                         \
        "v_add_f32 %0, %0, %1"                                             \
        : "=&v"(_s), "=&v"(_t) : "v"(X), "v"(Y), "v"(Z));                  \
    _s; })

#define PKD2(X01, Y01, Z01, K01, QXD, QYD, QZD, QQD, M2) ({                \
    f2 _d, _s;                                                             \
    asm("v_pk_mul_f32 %0, %2, %6\n\t"      /* kx*qx per half        */     \
        "v_pk_fma_f32 %0, %3, %7, %0\n\t"  /* + ky*qy               */     \
        "v_pk_fma_f32 %0, %4, %8, %0\n\t"  /* + kz*qz -> dot        */     \
        "v_pk_add_f32 %1, %5, %9\n\t"      /* kk+qq                 */     \
        "v_pk_fma_f32 %0, %0, %10, %1"     /* d2 = dot*(-2)+(kk+qq) */     \
        : "=&v"(_d), "=&v"(_s)                                             \
        : "v"(X01), "v"(Y01), "v"(Z01), "v"(K01),                          \
          "v"(QXD), "v"(QYD), "v"(QZD), "v"(QQD), "v"(M2));                \
    _d; })

// Branchy top-3 insert — VERBATIM R14..R18 (validated).
#define INS(S, D2, J) do {                                                 \
        float _v = (D2);                                                   \
        if (_v < b2##S) {                                                  \
            bool c0 = _v < b0##S, c1 = _v < b1##S;                         \
            b2##S = c1 ? b1##S : _v;                                       \
            i2##S = c1 ? i1##S : (J);                                      \
            b1##S = c0 ? b0##S : (c1 ? _v : b1##S);                        \
            i1##S = c0 ? i0##S : (c1 ? (J) : i1##S);                       \
            b0##S = c0 ? _v : b0##S;                                       \
            i0##S = c0 ? (J) : i0##S;                                      \
        } } while (0)

// ---------------------------------------------------------------------------
// Pack keys — VERBATIM R18.
// ---------------------------------------------------------------------------
__global__ __launch_bounds__(256) void pack_keys(
    const float* __restrict__ kxyz,   // (B, 3, N2)
    float4* __restrict__ keys4)       // (B, N2)
{
    const int b = blockIdx.x >> 3;
    const int j = (blockIdx.x & 7) * 256 + threadIdx.x;
    const float* kb = kxyz + (size_t)b * 3 * N2;
    float x = kb[j], y = kb[N2 + j], z = kb[2 * N2 + j];
    keys4[(size_t)b * N2 + j] = make_float4(x, y, z, NRM2(x, y, z));
}

// ---------------------------------------------------------------------------
// KNN — VERBATIM R18 (validated Q2 structure; knn+copy <= 37us per R16).
// ---------------------------------------------------------------------------
__global__ __launch_bounds__(512, 4) void knn_scan(
    const float* __restrict__ qxyz,   // (B, 3, N1)
    const float4* __restrict__ keys4, // (B, N2) packed
    const float* __restrict__ qfeat,  // (B, C1, N1)
    int*   __restrict__ nn_idx,       // (B*N1*4) packed
    float* __restrict__ nn_w,         // (B*N1*4) packed
    float* __restrict__ out)          // (B, CO, N1)
{
    __shared__ __align__(16) float skx[N2];
    __shared__ __align__(16) float sky[N2];
    __shared__ __align__(16) float skz[N2];
    __shared__ __align__(16) float skk[N2];
    __shared__ float pd[8][128][3];    // 12 KB
    __shared__ int   pi[8][128][3];    // 12 KB

    const int b    = blockIdx.x >> 6;       // 64 tiles of 128 queries
    const int tile = blockIdx.x & 63;
    const int n0   = tile * 128;
    const int tid  = threadIdx.x;
    const int w    = tid >> 6, lane = tid & 63;

    // stage keys (coalesced float4 from packed ws; values bit-identical)
    const float4* kb4 = keys4 + (size_t)b * N2;
    for (int j = tid; j < N2; j += 512) {
        float4 k4 = kb4[j];
        skx[j] = k4.x; sky[j] = k4.y; skz[j] = k4.z; skk[j] = k4.w;
    }
    __syncthreads();

    // two queries per lane
    const int na = n0 + lane, nb = n0 + 64 + lane;
    const float* qb = qxyz + (size_t)b * 3 * N1;
    const float qxA = qb[na], qyA = qb[N1 + na], qzA = qb[2 * N1 + na];
    const float qxB = qb[nb], qyB = qb[N1 + nb], qzB = qb[2 * N1 + nb];
    const float qqA = NRM2(qxA, qyA, qzA);
    const float qqB = NRM2(qxB, qyB, qzB);

    f2 qxdA, qydA, qzdA, qqdA, qxdB, qydB, qzdB, qqdB, m2;
    qxdA.x = qxA; qxdA.y = qxA;  qydA.x = qyA; qydA.y = qyA;
    qzdA.x = qzA; qzdA.y = qzA;  qqdA.x = qqA; qqdA.y = qqA;
    qxdB.x = qxB; qxdB.y = qxB;  qydB.x = qyB; qydB.y = qyB;
    qzdB.x = qzB; qzdB.y = qzB;  qqdB.x = qqB; qqdB.y = qqB;
    m2.x = -2.0f; m2.y = -2.0f;

    float b0A = 3.4e38f, b1A = 3.4e38f, b2A = 3.4e38f;
    float b0B = 3.4e38f, b1B = 3.4e38f, b2B = 3.4e38f;
    int   i0A = 0, i1A = 0, i2A = 0, i0B = 0, i1B = 0, i2B = 0;

    const int jlo = w * (N2 / 8);            // 256 keys per wave-chunk
    #pragma unroll 4
    for (int g = 0; g < (N2 / 8) / 4; ++g) {
        const int jb = jlo + g * 4;
        f4 x4 = *(const f4*)&skx[jb];        // wave-uniform b128 broadcast
        f4 y4 = *(const f4*)&sky[jb];
        f4 z4 = *(const f4*)&skz[jb];
        f4 k4 = *(const f4*)&skk[jb];
        f2 dA01 = PKD2(x4.xy, y4.xy, z4.xy, k4.xy, qxdA, qydA, qzdA, qqdA, m2);
        f2 dA23 = PKD2(x4.zw, y4.zw, z4.zw, k4.zw, qxdA, qydA, qzdA, qqdA, m2);
        f2 dB01 = PKD2(x4.xy, y4.xy, z4.xy, k4.xy, qxdB, qydB, qzdB, qqdB, m2);
        f2 dB23 = PKD2(x4.zw, y4.zw, z4.zw, k4.zw, qxdB, qydB, qzdB, qqdB, m2);
        INS(A, dA01.x, jb);     INS(A, dA01.y, jb + 1);
        INS(A, dA23.x, jb + 2); INS(A, dA23.y, jb + 3);
        INS(B, dB01.x, jb);     INS(B, dB01.y, jb + 1);
        INS(B, dB23.x, jb + 2); INS(B, dB23.y, jb + 3);
    }

    pd[w][lane][0] = b0A; pd[w][lane][1] = b1A; pd[w][lane][2] = b2A;
    pi[w][lane][0] = i0A; pi[w][lane][1] = i1A; pi[w][lane][2] = i2A;
    pd[w][64 + lane][0] = b0B; pd[w][64 + lane][1] = b1B; pd[w][64 + lane][2] = b2B;
    pi[w][64 + lane][0] = i0B; pi[w][64 + lane][1] = i1B; pi[w][64 + lane][2] = i2B;
    __syncthreads();

    if (tid < 128) {
        float m0 = 3.4e38f, m1 = 3.4e38f, m2s = 3.4e38f;
        int   j0 = 0, j1 = 0, j2 = 0;
        #pragma unroll
        for (int c = 0; c < 8; ++c) {
            #pragma unroll
            for (int s = 0; s < 3; ++s) {
                float d = pd[c][tid][s];
                int   i = pi[c][tid][s];
                if (d < m2s) {
                    bool c0 = d < m0, c1 = d < m1;
                    m2s = c1 ? m1 : d;               j2 = c1 ? j1 : i;
                    m1 = c0 ? m0 : (c1 ? d : m1);    j1 = c0 ? j0 : (c1 ? i : j1);
                    m0 = c0 ? d : m0;                j0 = c0 ? i  : j0;
                }
            }
        }
        // weights: mirror reference op order (R8-validated, packed store)
        float d0f = fmaxf(m0, 1e-10f), d1f = fmaxf(m1, 1e-10f), d2f = fmaxf(m2s, 1e-10f);
        float v0 = __fdiv_rn(1.0f, d0f), v1 = __fdiv_rn(1.0f, d1f), v2 = __fdiv_rn(1.0f, d2f);
        float s  = __fadd_rn(__fadd_rn(v0, v1), v2);
        const size_t g = (size_t)b * N1 + n0 + tid;
        *(int4*)  &nn_idx[g * 4] = make_int4(j0, j1, j2, 0);
        *(float4*)&nn_w  [g * 4] = make_float4(__fdiv_rn(v0, s), __fdiv_rn(v1, s),
                                               __fdiv_rn(v2, s), 0.0f);
    }

    // Folded qfeat copy (validated float4 stream; rides knn's idle HBM).
    const float4* qsrc = (const float4*)(qfeat + (size_t)b * C1 * N1);
    float4*       qdst = (float4*)(out + (size_t)b * CO * N1 + (size_t)C2 * N1);
    #pragma unroll
    for (int k = 0; k < 16; ++k) {
        const size_t r = (size_t)tile * 8192 + (size_t)k * 512 + tid;
        qdst[r] = qsrc[r];
    }
}

// ---------------------------------------------------------------------------
// Interp v8 — R18 body executed IREPS times (identical values every rep;
// barrier-separated; deterministic; graph-safe). Purpose: surface this
// kernel above the ~112us harness fills in BOTH rocprof passes so we get
// its VGPR/occupancy/VALUBusy/LDS-conflict/WRITE_SIZE counters — the data
// needed to attribute its ~68us (vs ~26us HBM floor) before changing it.
// ---------------------------------------------------------------------------
__global__ __launch_bounds__(256) void interp8(
    const float* __restrict__ kfeat,  // (B, C2, N2)
    const int*   __restrict__ nn_idx, // packed stride-4
    const float* __restrict__ nn_w,   // packed stride-4
    float* __restrict__ out)          // (B, CO, N1)
{
    __shared__ __align__(8) f2 skp01[N2];   // 16 KB: channels (c0,c1) per key
    __shared__ __align__(8) f2 skp23[N2];   // 16 KB: channels (c2,c3) per key
    const int b     = blockIdx.x & 7;       // XCD-pinned batch
    const int cg    = blockIdx.x >> 3;      // 0..127
    const int cbase = cg * CCH;
    const int tid   = threadIdx.x;

    #pragma unroll 1
    for (int rep = 0; rep < IREPS; ++rep) {
    __syncthreads();

    const float* kf = kfeat + (size_t)b * C2 * N2 + (size_t)cbase * N2;
    for (int j = tid; j < N2; j += 256) {
        f2 p01, p23;
        p01.x = kf[j];          p01.y = kf[N2 + j];
        p23.x = kf[2 * N2 + j]; p23.y = kf[3 * N2 + j];
        skp01[j] = p01;
        skp23[j] = p23;
    }
    __syncthreads();

    const int*   ib = nn_idx + (size_t)b * N1 * 4;
    const float* wb = nn_w   + (size_t)b * N1 * 4;
    float* ob = out + (size_t)b * CO * N1;

    #pragma unroll 4
    for (int t = 0; t < N1 / 256; ++t) {
        const int n = t * 256 + tid;
        const int4   iv = *(const int4*)  &ib[(size_t)n * 4];
        const float4 wv = *(const float4*)&wb[(size_t)n * 4];
        const f2 a01 = skp01[iv.x], a23 = skp23[iv.x];
        const f2 b01 = skp01[iv.y], b23 = skp23[iv.y];
        const f2 c01 = skp01[iv.z], c23 = skp23[iv.z];
        // per-channel: fmaf(w2,f2, fmaf(w1,f1, mul(w0,f0))) — validated order
        ob[(size_t)(cbase + 0) * N1 + n] =
            fmaf(wv.z, c01.x, fmaf(wv.y, b01.x, __fmul_rn(wv.x, a01.x)));
        ob[(size_t)(cbase + 1) * N1 + n] =
            fmaf(wv.z, c01.y, fmaf(wv.y, b01.y, __fmul_rn(wv.x, a01.y)));
        ob[(size_t)(cbase + 2) * N1 + n] =
            fmaf(wv.z, c23.x, fmaf(wv.y, b23.x, __fmul_rn(wv.x, a23.x)));
        ob[(size_t)(cbase + 3) * N1 + n] =
            fmaf(wv.z, c23.y, fmaf(wv.y, b23.y, __fmul_rn(wv.x, a23.y)));
    }
    }  // rep
}

extern "C" void kernel_launch(void* const* d_in, const int* in_sizes, int n_in,
                              void* d_out, int out_size, void* d_ws, size_t ws_size,
                              hipStream_t stream) {
    const float* qxyz  = (const float*)d_in[0];
    const float* kxyz  = (const float*)d_in[1];
    const float* qfeat = (const float*)d_in[2];
    const float* kfeat = (const float*)d_in[3];
    float* out = (float*)d_out;

    float*  ws     = (float*)d_ws;
    float4* keys4  = (float4*)ws;                                // 65536 f
    int*    nn_idx = (int*)(ws + (size_t)4 * NB * N2);           // 262144 i
    float*  nn_w   = ws + (size_t)4 * NB * N2 + (size_t)4 * NB * N1;

    pack_keys<<<NB * (N2 / 256), 256, 0, stream>>>(kxyz, keys4);
    knn_scan<<<NB * (N1 / 128), 512, 0, stream>>>(qxyz, keys4, qfeat,
                                                  nn_idx, nn_w, out);
    interp8<<<NB * (C2 / CCH), 256, 0, stream>>>(kfeat, nn_idx, nn_w, out);
}

// Round 21
// 103.099 us; speedup vs baseline: 1.5900x; 1.5900x over previous
//
#include <hip/hip_runtime.h>

#define NB 8
#define N1 8192
#define N2 2048
#define C1 256
#define C2 512
#define CO 768   // C1 + C2
#define CCH 4    // channels per interp block

typedef float f2 __attribute__((ext_vector_type(2)));
typedef float f4 __attribute__((ext_vector_type(4)));

// ws: keys4 (B*N2 float4 = 256 KB) | nn_idx (B*N1*4 ints = 1 MB) |
//     nn_w (B*N1*4 floats = 1 MB). Total 2.25 MB.  (R11..R18-exact layout)

// ---------------------------------------------------------------------------
// ASM-PINNED arithmetic — VERBATIM R14..R20 (validated, absmax 0.015625).
// ---------------------------------------------------------------------------
#define NRM2(X, Y, Z) ({                                                   \
    float _s, _t;                                                          \
    asm("v_mul_f32 %0, %2, %2\n\t"                                         \
        "v_mul_f32 %1, %3, %3\n\t"                                         \
        "v_add_f32 %0, %0, %1\n\t"                                         \
        "v_mul_f32 %1, %4, %4\n\t"                                         \
        "v_add_f32 %0, %0, %1"                                             \
        : "=&v"(_s), "=&v"(_t) : "v"(X), "v"(Y), "v"(Z));                  \
    _s; })

#define PKD2(X01, Y01, Z01, K01, QXD, QYD, QZD, QQD, M2) ({                \
    f2 _d, _s;                                                             \
    asm("v_pk_mul_f32 %0, %2, %6\n\t"      /* kx*qx per half        */     \
        "v_pk_fma_f32 %0, %3, %7, %0\n\t"  /* + ky*qy               */     \
        "v_pk_fma_f32 %0, %4, %8, %0\n\t"  /* + kz*qz -> dot        */     \
        "v_pk_add_f32 %1, %5, %9\n\t"      /* kk+qq                 */     \
        "v_pk_fma_f32 %0, %0, %10, %1"     /* d2 = dot*(-2)+(kk+qq) */     \
        : "=&v"(_d), "=&v"(_s)                                             \
        : "v"(X01), "v"(Y01), "v"(Z01), "v"(K01),                          \
          "v"(QXD), "v"(QYD), "v"(QZD), "v"(QQD), "v"(M2));                \
    _d; })

// Branchy top-3 insert — VERBATIM R14..R20 (validated).
#define INS(S, D2, J) do {                                                 \
        float _v = (D2);                                                   \
        if (_v < b2##S) {                                                  \
            bool c0 = _v < b0##S, c1 = _v < b1##S;                         \
            b2##S = c1 ? b1##S : _v;                                       \
            i2##S = c1 ? i1##S : (J);                                      \
            b1##S = c0 ? b0##S : (c1 ? _v : b1##S);                        \
            i1##S = c0 ? i0##S : (c1 ? (J) : i1##S);                       \
            b0##S = c0 ? _v : b0##S;                                       \
            i0##S = c0 ? (J) : i0##S;                                      \
        } } while (0)

// ---------------------------------------------------------------------------
// Pack keys — VERBATIM R18.
// ---------------------------------------------------------------------------
__global__ __launch_bounds__(256) void pack_keys(
    const float* __restrict__ kxyz,   // (B, 3, N2)
    float4* __restrict__ keys4)       // (B, N2)
{
    const int b = blockIdx.x >> 3;
    const int j = (blockIdx.x & 7) * 256 + threadIdx.x;
    const float* kb = kxyz + (size_t)b * 3 * N2;
    float x = kb[j], y = kb[N2 + j], z = kb[2 * N2 + j];
    keys4[(size_t)b * N2 + j] = make_float4(x, y, z, NRM2(x, y, z));
}

// ---------------------------------------------------------------------------
// KNN — R18 structure; ONE change: the folded qfeat copy is INTERLEAVED into
// the scan loop (R20 attribution: knn ~60us = scan ~35 [LDS/VALU, HBM idle]
// then copy ~25 [HBM, VALU idle] as sequential phases). Depth-4 rolling
// register pipeline: iteration t stores element t and prefetches t+4; the
// async global ops drain under the scan's VALU/LDS work. Scan arithmetic,
// key order, INS, merge, weights: byte-identical. Copy addresses identical
// (wrapped prefetches at t>=12 load in-bounds garbage that is never stored).
// ---------------------------------------------------------------------------
__global__ __launch_bounds__(512, 4) void knn_scan(
    const float* __restrict__ qxyz,   // (B, 3, N1)
    const float4* __restrict__ keys4, // (B, N2) packed
    const float* __restrict__ qfeat,  // (B, C1, N1)
    int*   __restrict__ nn_idx,       // (B*N1*4) packed
    float* __restrict__ nn_w,         // (B*N1*4) packed
    float* __restrict__ out)          // (B, CO, N1)
{
    __shared__ __align__(16) float skx[N2];
    __shared__ __align__(16) float sky[N2];
    __shared__ __align__(16) float skz[N2];
    __shared__ __align__(16) float skk[N2];
    __shared__ float pd[8][128][3];    // 12 KB
    __shared__ int   pi[8][128][3];    // 12 KB

    const int b    = blockIdx.x >> 6;       // 64 tiles of 128 queries
    const int tile = blockIdx.x & 63;
    const int n0   = tile * 128;
    const int tid  = threadIdx.x;
    const int w    = tid >> 6, lane = tid & 63;

    // stage keys (coalesced float4 from packed ws; values bit-identical)
    const float4* kb4 = keys4 + (size_t)b * N2;
    for (int j = tid; j < N2; j += 512) {
        float4 k4 = kb4[j];
        skx[j] = k4.x; sky[j] = k4.y; skz[j] = k4.z; skk[j] = k4.w;
    }
    __syncthreads();

    // two queries per lane
    const int na = n0 + lane, nb = n0 + 64 + lane;
    const float* qb = qxyz + (size_t)b * 3 * N1;
    const float qxA = qb[na], qyA = qb[N1 + na], qzA = qb[2 * N1 + na];
    const float qxB = qb[nb], qyB = qb[N1 + nb], qzB = qb[2 * N1 + nb];
    const float qqA = NRM2(qxA, qyA, qzA);
    const float qqB = NRM2(qxB, qyB, qzB);

    f2 qxdA, qydA, qzdA, qqdA, qxdB, qydB, qzdB, qqdB, m2;
    qxdA.x = qxA; qxdA.y = qxA;  qydA.x = qyA; qydA.y = qyA;
    qzdA.x = qzA; qzdA.y = qzA;  qqdA.x = qqA; qqdA.y = qqA;
    qxdB.x = qxB; qxdB.y = qxB;  qydB.x = qyB; qydB.y = qyB;
    qzdB.x = qzB; qzdB.y = qzB;  qqdB.x = qqB; qqdB.y = qqB;
    m2.x = -2.0f; m2.y = -2.0f;

    float b0A = 3.4e38f, b1A = 3.4e38f, b2A = 3.4e38f;
    float b0B = 3.4e38f, b1B = 3.4e38f, b2B = 3.4e38f;
    int   i0A = 0, i1A = 0, i2A = 0, i0B = 0, i1B = 0, i2B = 0;

    // rolling copy pipeline (depth 4): addresses identical to R18's copy
    const float4* qsrc = (const float4*)(qfeat + (size_t)b * C1 * N1);
    float4*       qdst = (float4*)(out + (size_t)b * CO * N1 + (size_t)C2 * N1);
    const size_t rbase = (size_t)tile * 8192 + tid;
    float4 c0 = qsrc[rbase];
    float4 c1 = qsrc[rbase + 512];
    float4 c2 = qsrc[rbase + 1024];
    float4 c3 = qsrc[rbase + 1536];

    const int jlo = w * (N2 / 8);            // 256 keys per wave-chunk
    #pragma unroll 1
    for (int t = 0; t < 16; ++t) {
        const int jb0 = jlo + t * 16;
        #pragma unroll
        for (int gg = 0; gg < 4; ++gg) {
            const int jb = jb0 + gg * 4;
            f4 x4 = *(const f4*)&skx[jb];    // wave-uniform b128 broadcast
            f4 y4 = *(const f4*)&sky[jb];
            f4 z4 = *(const f4*)&skz[jb];
            f4 k4 = *(const f4*)&skk[jb];
            f2 dA01 = PKD2(x4.xy, y4.xy, z4.xy, k4.xy, qxdA, qydA, qzdA, qqdA, m2);
            f2 dA23 = PKD2(x4.zw, y4.zw, z4.zw, k4.zw, qxdA, qydA, qzdA, qqdA, m2);
            f2 dB01 = PKD2(x4.xy, y4.xy, z4.xy, k4.xy, qxdB, qydB, qzdB, qqdB, m2);
            f2 dB23 = PKD2(x4.zw, y4.zw, z4.zw, k4.zw, qxdB, qydB, qzdB, qqdB, m2);
            INS(A, dA01.x, jb);     INS(A, dA01.y, jb + 1);
            INS(A, dA23.x, jb + 2); INS(A, dA23.y, jb + 3);
            INS(B, dB01.x, jb);     INS(B, dB01.y, jb + 1);
            INS(B, dB23.x, jb + 2); INS(B, dB23.y, jb + 3);
        }
        // copy: store element t, rotate, prefetch element t+4 (wrapped
        // prefetches at t>=12 are in-bounds reads that are never stored)
        qdst[rbase + (size_t)t * 512] = c0;
        c0 = c1; c1 = c2; c2 = c3;
        c3 = qsrc[rbase + (size_t)((t + 4) & 15) * 512];
    }

    pd[w][lane][0] = b0A; pd[w][lane][1] = b1A; pd[w][lane][2] = b2A;
    pi[w][lane][0] = i0A; pi[w][lane][1] = i1A; pi[w][lane][2] = i2A;
    pd[w][64 + lane][0] = b0B; pd[w][64 + lane][1] = b1B; pd[w][64 + lane][2] = b2B;
    pi[w][64 + lane][0] = i0B; pi[w][64 + lane][1] = i1B; pi[w][64 + lane][2] = i2B;
    __syncthreads();

    if (tid < 128) {
        float m0 = 3.4e38f, m1 = 3.4e38f, m2s = 3.4e38f;
        int   j0 = 0, j1 = 0, j2 = 0;
        #pragma unroll
        for (int c = 0; c < 8; ++c) {
            #pragma unroll
            for (int s = 0; s < 3; ++s) {
                float d = pd[c][tid][s];
                int   i = pi[c][tid][s];
                if (d < m2s) {
                    bool c0 = d < m0, c1 = d < m1;
                    m2s = c1 ? m1 : d;               j2 = c1 ? j1 : i;
                    m1 = c0 ? m0 : (c1 ? d : m1);    j1 = c0 ? j0 : (c1 ? i : j1);
                    m0 = c0 ? d : m0;                j0 = c0 ? i  : j0;
                }
            }
        }
        // weights: mirror reference op order (R8-validated, packed store)
        float d0f = fmaxf(m0, 1e-10f), d1f = fmaxf(m1, 1e-10f), d2f = fmaxf(m2s, 1e-10f);
        float v0 = __fdiv_rn(1.0f, d0f), v1 = __fdiv_rn(1.0f, d1f), v2 = __fdiv_rn(1.0f, d2f);
        float s  = __fadd_rn(__fadd_rn(v0, v1), v2);
        const size_t g = (size_t)b * N1 + n0 + tid;
        *(int4*)  &nn_idx[g * 4] = make_int4(j0, j1, j2, 0);
        *(float4*)&nn_w  [g * 4] = make_float4(__fdiv_rn(v0, s), __fdiv_rn(v1, s),
                                               __fdiv_rn(v2, s), 0.0f);
    }
}

// ---------------------------------------------------------------------------
// Interp v8 — VERBATIM R18 (validated; ~17us warm per R20 reps).
// ---------------------------------------------------------------------------
__global__ __launch_bounds__(256) void interp8(
    const float* __restrict__ kfeat,  // (B, C2, N2)
    const int*   __restrict__ nn_idx, // packed stride-4
    const float* __restrict__ nn_w,   // packed stride-4
    float* __restrict__ out)          // (B, CO, N1)
{
    __shared__ __align__(8) f2 skp01[N2];   // 16 KB: channels (c0,c1) per key
    __shared__ __align__(8) f2 skp23[N2];   // 16 KB: channels (c2,c3) per key
    const int b     = blockIdx.x & 7;       // XCD-pinned batch
    const int cg    = blockIdx.x >> 3;      // 0..127
    const int cbase = cg * CCH;
    const int tid   = threadIdx.x;

    const float* kf = kfeat + (size_t)b * C2 * N2 + (size_t)cbase * N2;
    for (int j = tid; j < N2; j += 256) {
        f2 p01, p23;
        p01.x = kf[j];          p01.y = kf[N2 + j];
        p23.x = kf[2 * N2 + j]; p23.y = kf[3 * N2 + j];
        skp01[j] = p01;
        skp23[j] = p23;
    }
    __syncthreads();

    const int*   ib = nn_idx + (size_t)b * N1 * 4;
    const float* wb = nn_w   + (size_t)b * N1 * 4;
    float* ob = out + (size_t)b * CO * N1;

    #pragma unroll 4
    for (int t = 0; t < N1 / 256; ++t) {
        const int n = t * 256 + tid;
        const int4   iv = *(const int4*)  &ib[(size_t)n * 4];
        const float4 wv = *(const float4*)&wb[(size_t)n * 4];
        const f2 a01 = skp01[iv.x], a23 = skp23[iv.x];
        const f2 b01 = skp01[iv.y], b23 = skp23[iv.y];
        const f2 c01 = skp01[iv.z], c23 = skp23[iv.z];
        // per-channel: fmaf(w2,f2, fmaf(w1,f1, mul(w0,f0))) — validated order
        ob[(size_t)(cbase + 0) * N1 + n] =
            fmaf(wv.z, c01.x, fmaf(wv.y, b01.x, __fmul_rn(wv.x, a01.x)));
        ob[(size_t)(cbase + 1) * N1 + n] =
            fmaf(wv.z, c01.y, fmaf(wv.y, b01.y, __fmul_rn(wv.x, a01.y)));
        ob[(size_t)(cbase + 2) * N1 + n] =
            fmaf(wv.z, c23.x, fmaf(wv.y, b23.x, __fmul_rn(wv.x, a23.x)));
        ob[(size_t)(cbase + 3) * N1 + n] =
            fmaf(wv.z, c23.y, fmaf(wv.y, b23.y, __fmul_rn(wv.x, a23.y)));
    }
}

extern "C" void kernel_launch(void* const* d_in, const int* in_sizes, int n_in,
                              void* d_out, int out_size, void* d_ws, size_t ws_size,
                              hipStream_t stream) {
    const float* qxyz  = (const float*)d_in[0];
    const float* kxyz  = (const float*)d_in[1];
    const float* qfeat = (const float*)d_in[2];
    const float* kfeat = (const float*)d_in[3];
    float* out = (float*)d_out;

    float*  ws     = (float*)d_ws;
    float4* keys4  = (float4*)ws;                                // 65536 f
    int*    nn_idx = (int*)(ws + (size_t)4 * NB * N2);           // 262144 i
    float*  nn_w   = ws + (size_t)4 * NB * N2 + (size_t)4 * NB * N1;

    pack_keys<<<NB * (N2 / 256), 256, 0, stream>>>(kxyz, keys4);
    knn_scan<<<NB * (N1 / 128), 512, 0, stream>>>(qxyz, keys4, qfeat,
                                                  nn_idx, nn_w, out);
    interp8<<<NB * (C2 / CCH), 256, 0, stream>>>(kfeat, nn_idx, nn_w, out);
}

// Round 22
// 98.736 us; speedup vs baseline: 1.6602x; 1.0442x over previous
//
#include <hip/hip_runtime.h>

#define NB 8
#define N1 8192
#define N2 2048
#define C1 256
#define C2 512
#define CO 768   // C1 + C2
#define CCH 4    // channels per interp block

typedef float f2 __attribute__((ext_vector_type(2)));
typedef float f4 __attribute__((ext_vector_type(4)));

// ws: nn_idx (B*N1*4 ints = 1 MB) | nn_w (B*N1*4 floats = 1 MB) = 2 MB.

// ---------------------------------------------------------------------------
// ASM-PINNED arithmetic — VERBATIM R14..R21 (validated, absmax 0.015625).
// ---------------------------------------------------------------------------
#define NRM2(X, Y, Z) ({                                                   \
    float _s, _t;                                                          \
    asm("v_mul_f32 %0, %2, %2\n\t"                                         \
        "v_mul_f32 %1, %3, %3\n\t"                                         \
        "v_add_f32 %0, %0, %1\n\t"                                         \
        "v_mul_f32 %1, %4, %4\n\t"                                         \
        "v_add_f32 %0, %0, %1"                                             \
        : "=&v"(_s), "=&v"(_t) : "v"(X), "v"(Y), "v"(Z));                  \
    _s; })

#define PKD2(X01, Y01, Z01, K01, QXD, QYD, QZD, QQD, M2) ({                \
    f2 _d, _s;                                                             \
    asm("v_pk_mul_f32 %0, %2, %6\n\t"      /* kx*qx per half        */     \
        "v_pk_fma_f32 %0, %3, %7, %0\n\t"  /* + ky*qy               */     \
        "v_pk_fma_f32 %0, %4, %8, %0\n\t"  /* + kz*qz -> dot        */     \
        "v_pk_add_f32 %1, %5, %9\n\t"      /* kk+qq                 */     \
        "v_pk_fma_f32 %0, %0, %10, %1"     /* d2 = dot*(-2)+(kk+qq) */     \
        : "=&v"(_d), "=&v"(_s)                                             \
        : "v"(X01), "v"(Y01), "v"(Z01), "v"(K01),                          \
          "v"(QXD), "v"(QYD), "v"(QZD), "v"(QQD), "v"(M2));                \
    _d; })

// Branchy top-3 insert — VERBATIM R14..R21 (validated).
#define INS(S, D2, J) do {                                                 \
        float _v = (D2);                                                   \
        if (_v < b2##S) {                                                  \
            bool c0 = _v < b0##S, c1 = _v < b1##S;                         \
            b2##S = c1 ? b1##S : _v;                                       \
            i2##S = c1 ? i1##S : (J);                                      \
            b1##S = c0 ? b0##S : (c1 ? _v : b1##S);                        \
            i1##S = c0 ? i0##S : (c1 ? (J) : i1##S);                       \
            b0##S = c0 ? _v : b0##S;                                       \
            i0##S = c0 ? (J) : i0##S;                                      \
        } } while (0)

// ---------------------------------------------------------------------------
// KNN — R21 structure; ONE change: keys staged directly from kxyz with
// pinned NRM2 (the R12-validated staging), eliminating the pack_keys kernel,
// its launch gap, and the keys4 ws round-trip. NRM2 is asm-pinned, so the
// staged (x,y,z,kk) values are bit-identical to the packed-ws path.
// Scan/INS/merge/weights/copy-interleave: byte-identical to R21.
// ---------------------------------------------------------------------------
__global__ __launch_bounds__(512, 4) void knn_scan(
    const float* __restrict__ qxyz,   // (B, 3, N1)
    const float* __restrict__ kxyz,   // (B, 3, N2)
    const float* __restrict__ qfeat,  // (B, C1, N1)
    int*   __restrict__ nn_idx,       // (B*N1*4) packed
    float* __restrict__ nn_w,         // (B*N1*4) packed
    float* __restrict__ out)          // (B, CO, N1)
{
    __shared__ __align__(16) float skx[N2];
    __shared__ __align__(16) float sky[N2];
    __shared__ __align__(16) float skz[N2];
    __shared__ __align__(16) float skk[N2];
    __shared__ float pd[8][128][3];    // 12 KB
    __shared__ int   pi[8][128][3];    // 12 KB

    const int b    = blockIdx.x >> 6;       // 64 tiles of 128 queries
    const int tile = blockIdx.x & 63;
    const int n0   = tile * 128;
    const int tid  = threadIdx.x;
    const int w    = tid >> 6, lane = tid & 63;

    // stage keys from kxyz with pinned |k|^2 (R12-validated pattern)
    const float* kb = kxyz + (size_t)b * 3 * N2;
    for (int j = tid; j < N2; j += 512) {
        float x = kb[j], y = kb[N2 + j], z = kb[2 * N2 + j];
        skx[j] = x; sky[j] = y; skz[j] = z;
        skk[j] = NRM2(x, y, z);
    }
    __syncthreads();

    // two queries per lane
    const int na = n0 + lane, nb = n0 + 64 + lane;
    const float* qb = qxyz + (size_t)b * 3 * N1;
    const float qxA = qb[na], qyA = qb[N1 + na], qzA = qb[2 * N1 + na];
    const float qxB = qb[nb], qyB = qb[N1 + nb], qzB = qb[2 * N1 + nb];
    const float qqA = NRM2(qxA, qyA, qzA);
    const float qqB = NRM2(qxB, qyB, qzB);

    f2 qxdA, qydA, qzdA, qqdA, qxdB, qydB, qzdB, qqdB, m2;
    qxdA.x = qxA; qxdA.y = qxA;  qydA.x = qyA; qydA.y = qyA;
    qzdA.x = qzA; qzdA.y = qzA;  qqdA.x = qqA; qqdA.y = qqA;
    qxdB.x = qxB; qxdB.y = qxB;  qydB.x = qyB; qydB.y = qyB;
    qzdB.x = qzB; qzdB.y = qzB;  qqdB.x = qqB; qqdB.y = qqB;
    m2.x = -2.0f; m2.y = -2.0f;

    float b0A = 3.4e38f, b1A = 3.4e38f, b2A = 3.4e38f;
    float b0B = 3.4e38f, b1B = 3.4e38f, b2B = 3.4e38f;
    int   i0A = 0, i1A = 0, i2A = 0, i0B = 0, i1B = 0, i2B = 0;

    // rolling copy pipeline (depth 4) — VERBATIM R21
    const float4* qsrc = (const float4*)(qfeat + (size_t)b * C1 * N1);
    float4*       qdst = (float4*)(out + (size_t)b * CO * N1 + (size_t)C2 * N1);
    const size_t rbase = (size_t)tile * 8192 + tid;
    float4 c0 = qsrc[rbase];
    float4 c1 = qsrc[rbase + 512];
    float4 c2 = qsrc[rbase + 1024];
    float4 c3 = qsrc[rbase + 1536];

    const int jlo = w * (N2 / 8);            // 256 keys per wave-chunk
    #pragma unroll 1
    for (int t = 0; t < 16; ++t) {
        const int jb0 = jlo + t * 16;
        #pragma unroll
        for (int gg = 0; gg < 4; ++gg) {
            const int jb = jb0 + gg * 4;
            f4 x4 = *(const f4*)&skx[jb];    // wave-uniform b128 broadcast
            f4 y4 = *(const f4*)&sky[jb];
            f4 z4 = *(const f4*)&skz[jb];
            f4 k4 = *(const f4*)&skk[jb];
            f2 dA01 = PKD2(x4.xy, y4.xy, z4.xy, k4.xy, qxdA, qydA, qzdA, qqdA, m2);
            f2 dA23 = PKD2(x4.zw, y4.zw, z4.zw, k4.zw, qxdA, qydA, qzdA, qqdA, m2);
            f2 dB01 = PKD2(x4.xy, y4.xy, z4.xy, k4.xy, qxdB, qydB, qzdB, qqdB, m2);
            f2 dB23 = PKD2(x4.zw, y4.zw, z4.zw, k4.zw, qxdB, qydB, qzdB, qqdB, m2);
            INS(A, dA01.x, jb);     INS(A, dA01.y, jb + 1);
            INS(A, dA23.x, jb + 2); INS(A, dA23.y, jb + 3);
            INS(B, dB01.x, jb);     INS(B, dB01.y, jb + 1);
            INS(B, dB23.x, jb + 2); INS(B, dB23.y, jb + 3);
        }
        // copy: store element t, rotate, prefetch element t+4 (wrapped
        // prefetches at t>=12 are in-bounds reads that are never stored)
        qdst[rbase + (size_t)t * 512] = c0;
        c0 = c1; c1 = c2; c2 = c3;
        c3 = qsrc[rbase + (size_t)((t + 4) & 15) * 512];
    }

    pd[w][lane][0] = b0A; pd[w][lane][1] = b1A; pd[w][lane][2] = b2A;
    pi[w][lane][0] = i0A; pi[w][lane][1] = i1A; pi[w][lane][2] = i2A;
    pd[w][64 + lane][0] = b0B; pd[w][64 + lane][1] = b1B; pd[w][64 + lane][2] = b2B;
    pi[w][64 + lane][0] = i0B; pi[w][64 + lane][1] = i1B; pi[w][64 + lane][2] = i2B;
    __syncthreads();

    if (tid < 128) {
        float m0 = 3.4e38f, m1 = 3.4e38f, m2s = 3.4e38f;
        int   j0 = 0, j1 = 0, j2 = 0;
        #pragma unroll
        for (int c = 0; c < 8; ++c) {
            #pragma unroll
            for (int s = 0; s < 3; ++s) {
                float d = pd[c][tid][s];
                int   i = pi[c][tid][s];
                if (d < m2s) {
                    bool c0 = d < m0, c1 = d < m1;
                    m2s = c1 ? m1 : d;               j2 = c1 ? j1 : i;
                    m1 = c0 ? m0 : (c1 ? d : m1);    j1 = c0 ? j0 : (c1 ? i : j1);
                    m0 = c0 ? d : m0;                j0 = c0 ? i  : j0;
                }
            }
        }
        // weights: mirror reference op order (R8-validated, packed store)
        float d0f = fmaxf(m0, 1e-10f), d1f = fmaxf(m1, 1e-10f), d2f = fmaxf(m2s, 1e-10f);
        float v0 = __fdiv_rn(1.0f, d0f), v1 = __fdiv_rn(1.0f, d1f), v2 = __fdiv_rn(1.0f, d2f);
        float s  = __fadd_rn(__fadd_rn(v0, v1), v2);
        const size_t g = (size_t)b * N1 + n0 + tid;
        *(int4*)  &nn_idx[g * 4] = make_int4(j0, j1, j2, 0);
        *(float4*)&nn_w  [g * 4] = make_float4(__fdiv_rn(v0, s), __fdiv_rn(v1, s),
                                               __fdiv_rn(v2, s), 0.0f);
    }
}

// ---------------------------------------------------------------------------
// Interp v8 — VERBATIM R18/R21 (validated; ~17us warm, ~HBM floor cold).
// ---------------------------------------------------------------------------
__global__ __launch_bounds__(256) void interp8(
    const float* __restrict__ kfeat,  // (B, C2, N2)
    const int*   __restrict__ nn_idx, // packed stride-4
    const float* __restrict__ nn_w,   // packed stride-4
    float* __restrict__ out)          // (B, CO, N1)
{
    __shared__ __align__(8) f2 skp01[N2];   // 16 KB: channels (c0,c1) per key
    __shared__ __align__(8) f2 skp23[N2];   // 16 KB: channels (c2,c3) per key
    const int b     = blockIdx.x & 7;       // XCD-pinned batch
    const int cg    = blockIdx.x >> 3;      // 0..127
    const int cbase = cg * CCH;
    const int tid   = threadIdx.x;

    const float* kf = kfeat + (size_t)b * C2 * N2 + (size_t)cbase * N2;
    for (int j = tid; j < N2; j += 256) {
        f2 p01, p23;
        p01.x = kf[j];          p01.y = kf[N2 + j];
        p23.x = kf[2 * N2 + j]; p23.y = kf[3 * N2 + j];
        skp01[j] = p01;
        skp23[j] = p23;
    }
    __syncthreads();

    const int*   ib = nn_idx + (size_t)b * N1 * 4;
    const float* wb = nn_w   + (size_t)b * N1 * 4;
    float* ob = out + (size_t)b * CO * N1;

    #pragma unroll 4
    for (int t = 0; t < N1 / 256; ++t) {
        const int n = t * 256 + tid;
        const int4   iv = *(const int4*)  &ib[(size_t)n * 4];
        const float4 wv = *(const float4*)&wb[(size_t)n * 4];
        const f2 a01 = skp01[iv.x], a23 = skp23[iv.x];
        const f2 b01 = skp01[iv.y], b23 = skp23[iv.y];
        const f2 c01 = skp01[iv.z], c23 = skp23[iv.z];
        // per-channel: fmaf(w2,f2, fmaf(w1,f1, mul(w0,f0))) — validated order
        ob[(size_t)(cbase + 0) * N1 + n] =
            fmaf(wv.z, c01.x, fmaf(wv.y, b01.x, __fmul_rn(wv.x, a01.x)));
        ob[(size_t)(cbase + 1) * N1 + n] =
            fmaf(wv.z, c01.y, fmaf(wv.y, b01.y, __fmul_rn(wv.x, a01.y)));
        ob[(size_t)(cbase + 2) * N1 + n] =
            fmaf(wv.z, c23.x, fmaf(wv.y, b23.x, __fmul_rn(wv.x, a23.x)));
        ob[(size_t)(cbase + 3) * N1 + n] =
            fmaf(wv.z, c23.y, fmaf(wv.y, b23.y, __fmul_rn(wv.x, a23.y)));
    }
}

extern "C" void kernel_launch(void* const* d_in, const int* in_sizes, int n_in,
                              void* d_out, int out_size, void* d_ws, size_t ws_size,
                              hipStream_t stream) {
    const float* qxyz  = (const float*)d_in[0];
    const float* kxyz  = (const float*)d_in[1];
    const float* qfeat = (const float*)d_in[2];
    const float* kfeat = (const float*)d_in[3];
    float* out = (float*)d_out;

    int*   nn_idx = (int*)d_ws;                              // 4*B*N1 ints
    float* nn_w   = (float*)d_ws + (size_t)4 * NB * N1;      // 4*B*N1 floats

    knn_scan<<<NB * (N1 / 128), 512, 0, stream>>>(qxyz, kxyz, qfeat,
                                                  nn_idx, nn_w, out);
    interp8<<<NB * (C2 / CCH), 256, 0, stream>>>(kfeat, nn_idx, nn_w, out);
}